// Round 2
// baseline (892.415 us; speedup 1.0000x reference)
//
#include <hip/hip_runtime.h>
#include <hip/hip_bf16.h>
#include <stdint.h>

typedef __hip_bfloat16 bf16;
typedef __attribute__((ext_vector_type(4))) float f32x4;
typedef __attribute__((ext_vector_type(8))) short bf16x8;

// Problem constants
#define BB   8
#define TT   2048
#define DD   1024
#define MM   (BB * TT)   // 16384 rows

enum { EPI_Q = 0, EPI_K, EPI_V, EPI_ND, EPI_MLP1, EPI_MLP2 };

static __device__ __forceinline__ void async_ld16(const bf16* g, bf16* l) {
  __builtin_amdgcn_global_load_lds(
      (const __attribute__((address_space(1))) void*)g,
      (__attribute__((address_space(3))) void*)l, 16, 0, 0);
}

// ---------------------------------------------------------------------------
// Universal GEMM: C[M,N] = A[M,K] @ B[N,K]^T, A/B bf16 row-major (K inner).
// 128x128 tile, BK=32, 256 threads (4 waves, 2x2), each wave 64x64 via
// 4x4 grid of 16x16x32 MFMAs. m97 structure: global_load_lds width-16.
// ---------------------------------------------------------------------------
template<int EPI>
__global__ __launch_bounds__(256, 2)
void gemm_bt(const bf16* __restrict__ A, const bf16* __restrict__ B,
             int M, int N, int K,
             long long strideAz, long long strideBz,
             float* __restrict__ Cf,
             bf16* __restrict__ Cb, long long strideCz,
             const float* __restrict__ bias,
             const float* __restrict__ add,
             bf16* __restrict__ ekv)
{
  (void)M;
  __shared__ __align__(16) bf16 As[128 * 32];
  __shared__ __align__(16) bf16 Bs[128 * 32];

  const int tid  = threadIdx.x;
  const int wave = tid >> 6;
  const int lane = tid & 63;
  const int bn = blockIdx.x, bm = blockIdx.y, bz = blockIdx.z;
  A += (size_t)bz * strideAz;
  B += (size_t)bz * strideBz;

  const int wm = (wave >> 1) * 64;   // wave's 64x64 sub-tile
  const int wn = (wave & 1) * 64;

  // staging: each wave stages 32 rows of As and Bs; 16 rows per instr,
  // lane l -> row l>>2, byte (l&3)*16 within row (rows are 64B).
  const int sr = lane >> 2;
  const int sc = (lane & 3) * 8;
  const size_t a_row = (size_t)bm * 128 + wave * 32 + sr;
  const size_t b_row = (size_t)bn * 128 + wave * 32 + sr;
  const bf16* Ag0 = A + a_row * K + sc;
  const bf16* Ag1 = Ag0 + (size_t)16 * K;
  const bf16* Bg0 = B + b_row * K + sc;
  const bf16* Bg1 = Bg0 + (size_t)16 * K;
  bf16* Al0 = &As[(wave * 32) * 32];
  bf16* Al1 = Al0 + 16 * 32;
  bf16* Bl0 = &Bs[(wave * 32) * 32];
  bf16* Bl1 = Bl0 + 16 * 32;

  const int fm = lane & 15;          // fragment row (A) / row-in-Bs (B^T col)
  const int fk = (lane >> 4) * 8;    // fragment k offset

  f32x4 acc[4][4];
#pragma unroll
  for (int i = 0; i < 4; ++i)
#pragma unroll
    for (int j = 0; j < 4; ++j) acc[i][j] = {0.f, 0.f, 0.f, 0.f};

  for (int k0 = 0; k0 < K; k0 += 32) {
    async_ld16(Ag0 + k0, Al0);
    async_ld16(Ag1 + k0, Al1);
    async_ld16(Bg0 + k0, Bl0);
    async_ld16(Bg1 + k0, Bl1);
    __builtin_amdgcn_s_waitcnt(0);
    __syncthreads();

    bf16x8 af[4], bfv[4];
#pragma unroll
    for (int i = 0; i < 4; ++i) {
      af[i]  = *(const bf16x8*)&As[(wm + i * 16 + fm) * 32 + fk];
      bfv[i] = *(const bf16x8*)&Bs[(wn + i * 16 + fm) * 32 + fk];
    }
#pragma unroll
    for (int i = 0; i < 4; ++i)
#pragma unroll
      for (int j = 0; j < 4; ++j)
        acc[i][j] = __builtin_amdgcn_mfma_f32_16x16x32_bf16(
            af[i], bfv[j], acc[i][j], 0, 0, 0);
    __syncthreads();
  }

  // epilogue: C/D layout col=lane&15, row=(lane>>4)*4+reg
  const int cr = (lane >> 4) * 4;
  const int cc = lane & 15;
#pragma unroll
  for (int i = 0; i < 4; ++i) {
#pragma unroll
    for (int j = 0; j < 4; ++j) {
#pragma unroll
      for (int r = 0; r < 4; ++r) {
        const int gm = bm * 128 + wm + i * 16 + cr + r;
        const int gn = bn * 128 + wn + j * 16 + cc;
        float v = acc[i][j][r];
        if constexpr (EPI == EPI_Q) {
          v += bias[gn];
          Cb[(size_t)gm * N + gn] = __float2bfloat16(v);
        } else if constexpr (EPI == EPI_K) {
          // gm = d, gn = global s. ekvT[b][1024+d][t] = exp(k)
          v = __expf(v + bias[gm]);
          const int b = gn >> 11, t = gn & (TT - 1);
          ekv[((size_t)b << 22) + (size_t)(1024 + gm) * TT + t] =
              __float2bfloat16(v);
        } else if constexpr (EPI == EPI_V) {
          // ekvT[b][d][t] = ek * v
          v += bias[gm];
          const int b = gn >> 11, t = gn & (TT - 1);
          const size_t base = ((size_t)b << 22);
          const float ek =
              __bfloat162float(ekv[base + (size_t)(1024 + gm) * TT + t]);
          ekv[base + (size_t)gm * TT + t] = __float2bfloat16(v * ek);
        } else if constexpr (EPI == EPI_ND) {
          Cb[(size_t)bz * strideCz + (size_t)gm * N + gn] =
              __float2bfloat16(v);
        } else if constexpr (EPI == EPI_MLP1) {
          v = fmaxf(v + bias[gn], 0.0f);
          Cb[(size_t)gm * N + gn] = __float2bfloat16(v);
        } else {  // EPI_MLP2: add == Cf aliasing is safe (read-then-write
          // of the same element within the same thread)
          v += bias[gn] + add[(size_t)gm * N + gn];
          Cf[(size_t)gm * N + gn] = v;
        }
      }
    }
  }
}

// ---------------------------------------------------------------------------
// Transpose + cast fp32 [K,N] -> bf16 [N,K] (LDS tiled)
// ---------------------------------------------------------------------------
__global__ __launch_bounds__(256)
void transpose_cast(const float* __restrict__ W, bf16* __restrict__ Wt,
                    int K, int N)
{
  __shared__ float tile[32][33];
  const int n0 = blockIdx.x * 32, k0 = blockIdx.y * 32;
  const int tx = threadIdx.x, ty = threadIdx.y;  // 32 x 8
#pragma unroll
  for (int i = 0; i < 32; i += 8)
    tile[ty + i][tx] = W[(size_t)(k0 + ty + i) * N + n0 + tx];
  __syncthreads();
#pragma unroll
  for (int i = 0; i < 32; i += 8)
    Wt[(size_t)(n0 + ty + i) * K + k0 + tx] =
        __float2bfloat16(tile[tx][ty + i]);
}

// ---------------------------------------------------------------------------
// ew = exp(pos_bias) as bf16 (global max cancels in num/den ratio)
// ---------------------------------------------------------------------------
__global__ __launch_bounds__(256)
void ew_kernel(const float* __restrict__ pb, bf16* __restrict__ ew)
{
  const size_t gid = (size_t)blockIdx.x * 256 + threadIdx.x;
  const float4 v = *(const float4*)(pb + gid * 4);
  union { bf16 h[4]; unsigned long long u; } pk;
  pk.h[0] = __float2bfloat16(__expf(v.x));
  pk.h[1] = __float2bfloat16(__expf(v.y));
  pk.h[2] = __float2bfloat16(__expf(v.z));
  pk.h[3] = __float2bfloat16(__expf(v.w));
  *(unsigned long long*)(ew + gid * 4) = pk.u;
}

// ---------------------------------------------------------------------------
// LayerNorm over D=1024, one block per row, output bf16
// ---------------------------------------------------------------------------
__global__ __launch_bounds__(256)
void ln_kernel(const float* __restrict__ x, const float* __restrict__ g,
               const float* __restrict__ b, bf16* __restrict__ out)
{
  const int row = blockIdx.x;
  const int tid = threadIdx.x;
  const float4 v = ((const float4*)(x + (size_t)row * DD))[tid];
  float s  = v.x + v.y + v.z + v.w;
  float s2 = v.x * v.x + v.y * v.y + v.z * v.z + v.w * v.w;
#pragma unroll
  for (int o = 32; o; o >>= 1) {
    s  += __shfl_down(s, o);
    s2 += __shfl_down(s2, o);
  }
  __shared__ float red[8];
  if ((tid & 63) == 0) { red[tid >> 6] = s; red[4 + (tid >> 6)] = s2; }
  __syncthreads();
  const float ts  = red[0] + red[1] + red[2] + red[3];
  const float ts2 = red[4] + red[5] + red[6] + red[7];
  const float mu = ts * (1.0f / DD);
  const float rs = rsqrtf(ts2 * (1.0f / DD) - mu * mu + 1e-5f);
  const float4 gv = ((const float4*)g)[tid];
  const float4 bv = ((const float4*)b)[tid];
  union { bf16 h[4]; unsigned long long u; } pk;
  pk.h[0] = __float2bfloat16((v.x - mu) * rs * gv.x + bv.x);
  pk.h[1] = __float2bfloat16((v.y - mu) * rs * gv.y + bv.y);
  pk.h[2] = __float2bfloat16((v.z - mu) * rs * gv.z + bv.z);
  pk.h[3] = __float2bfloat16((v.w - mu) * rs * gv.w + bv.w);
  ((unsigned long long*)(out + (size_t)row * DD))[tid] = pk.u;
}

// ---------------------------------------------------------------------------
// x2 = sigmoid(q) * num/den + x   (x2 aliases d_out)
// ---------------------------------------------------------------------------
__global__ __launch_bounds__(256)
void combine_kernel(const bf16* __restrict__ q, const bf16* __restrict__ nd,
                    const float* __restrict__ x, float* __restrict__ x2)
{
  const size_t gid = (size_t)blockIdx.x * 256 + threadIdx.x;
  const int m = (int)(gid >> 8);
  const int c = (int)(gid & 255) * 4;
  const bf16* ndr = nd + (size_t)m * 2048;
  union { unsigned long long u; bf16 h[4]; } un, ud, uq;
  un.u = *(const unsigned long long*)(ndr + c);
  ud.u = *(const unsigned long long*)(ndr + 1024 + c);
  uq.u = *(const unsigned long long*)(q + (size_t)m * DD + c);
  const float4 xv = *(const float4*)(x + (size_t)m * DD + c);
  float4 o;
  o.x = xv.x + (__bfloat162float(un.h[0]) / __bfloat162float(ud.h[0])) /
                   (1.0f + __expf(-__bfloat162float(uq.h[0])));
  o.y = xv.y + (__bfloat162float(un.h[1]) / __bfloat162float(ud.h[1])) /
                   (1.0f + __expf(-__bfloat162float(uq.h[1])));
  o.z = xv.z + (__bfloat162float(un.h[2]) / __bfloat162float(ud.h[2])) /
                   (1.0f + __expf(-__bfloat162float(uq.h[2])));
  o.w = xv.w + (__bfloat162float(un.h[3]) / __bfloat162float(ud.h[3])) /
                   (1.0f + __expf(-__bfloat162float(uq.h[3])));
  *(float4*)(x2 + (size_t)m * DD + c) = o;
}

// ---------------------------------------------------------------------------
extern "C" void kernel_launch(void* const* d_in, const int* in_sizes, int n_in,
                              void* d_out, int out_size, void* d_ws,
                              size_t ws_size, hipStream_t stream)
{
  (void)in_sizes; (void)n_in; (void)out_size; (void)ws_size;
  const float* x   = (const float*)d_in[0];
  const float* Wq  = (const float*)d_in[1];
  const float* bq  = (const float*)d_in[2];
  const float* Wk  = (const float*)d_in[3];
  const float* bk  = (const float*)d_in[4];
  const float* Wv  = (const float*)d_in[5];
  const float* bv  = (const float*)d_in[6];
  const float* pb  = (const float*)d_in[7];
  const float* g1  = (const float*)d_in[8];
  const float* be1 = (const float*)d_in[9];
  const float* W1  = (const float*)d_in[10];
  const float* bm1 = (const float*)d_in[11];
  const float* W2  = (const float*)d_in[12];
  const float* bm2 = (const float*)d_in[13];
  const float* g2  = (const float*)d_in[14];
  const float* be2 = (const float*)d_in[15];
  float* out = (float*)d_out;

  // ---- workspace layout: 222 MiB total ----
  const size_t MiB = 1024 * 1024;
  char* w = (char*)d_ws;
  bf16* hbf = (bf16*)w;  w += (size_t)MM * DD * 2;        // 32 MiB (h, then h2)
  bf16* wqt = (bf16*)w;  w += (size_t)DD * DD * 2;        // 2 MiB
  bf16* wkt = (bf16*)w;  w += (size_t)DD * DD * 2;
  bf16* wvt = (bf16*)w;  w += (size_t)DD * DD * 2;
  bf16* w1t = (bf16*)w;  w += (size_t)4096 * DD * 2;      // 8 MiB
  bf16* w2t = (bf16*)w;  w += (size_t)DD * 4096 * 2;      // 8 MiB
  // scratch region (168 MiB), fully dead after combine_kernel:
  char* scr = w;
  bf16* qbf = (bf16*)scr;                                  // 32 MiB
  bf16* ewb = (bf16*)(scr + 32 * MiB);                     // 8 MiB
  bf16* ekv = (bf16*)(scr + 40 * MiB);   // 64 MiB [b][2048: 0..1023=ek*v, 1024..2047=ek][t]
  bf16* nd  = (bf16*)(scr + 104 * MiB);  // 64 MiB [b][t][2048: num|den]
  bf16* mid = (bf16*)scr;                // 128 MiB, overlays scratch after combine
  float* x2 = out;                       // alias: residual lives in d_out

  const dim3 tb(32, 8);
  transpose_cast<<<dim3(DD / 32, DD / 32), tb, 0, stream>>>(Wq, wqt, DD, DD);
  transpose_cast<<<dim3(DD / 32, DD / 32), tb, 0, stream>>>(Wk, wkt, DD, DD);
  transpose_cast<<<dim3(DD / 32, DD / 32), tb, 0, stream>>>(Wv, wvt, DD, DD);
  transpose_cast<<<dim3(4096 / 32, DD / 32), tb, 0, stream>>>(W1, w1t, DD, 4096);
  transpose_cast<<<dim3(DD / 32, 4096 / 32), tb, 0, stream>>>(W2, w2t, 4096, DD);

  ew_kernel<<<(TT * TT / 4) / 256, 256, 0, stream>>>(pb, ewb);
  ln_kernel<<<MM, 256, 0, stream>>>(x, g1, be1, hbf);

  // q = h @ Wq + bq  -> qbf [16384,1024] bf16
  gemm_bt<EPI_Q><<<dim3(DD / 128, MM / 128, 1), 256, 0, stream>>>(
      hbf, wqt, MM, DD, DD, 0, 0, nullptr, qbf, 0, bq, nullptr, nullptr);
  // ek^T: C[d, s] = Wkt @ h^T, epilogue exp -> ekv rows 1024..2047
  gemm_bt<EPI_K><<<dim3(MM / 128, DD / 128, 1), 256, 0, stream>>>(
      wkt, hbf, DD, MM, DD, 0, 0, nullptr, nullptr, 0, bk, nullptr, ekv);
  // v^T: epilogue *ek -> ekv rows 0..1023
  gemm_bt<EPI_V><<<dim3(MM / 128, DD / 128, 1), 256, 0, stream>>>(
      wvt, hbf, DD, MM, DD, 0, 0, nullptr, nullptr, 0, bv, nullptr, ekv);
  // nd[b] = ew @ ekv[b]^T : [2048,2048] bf16 per batch
  gemm_bt<EPI_ND><<<dim3(TT / 128, TT / 128, BB), 256, 0, stream>>>(
      ewb, ekv, TT, TT, TT, 0, (long long)TT * TT, nullptr, nd,
      (long long)TT * TT, nullptr, nullptr, nullptr);

  combine_kernel<<<MM, 256, 0, stream>>>(qbf, nd, x, x2);
  ln_kernel<<<MM, 256, 0, stream>>>(x2, g2, be2, hbf);

  // mid = relu(h2 @ W1 + b1) bf16 [16384,4096]
  gemm_bt<EPI_MLP1><<<dim3(4096 / 128, MM / 128, 1), 256, 0, stream>>>(
      hbf, w1t, MM, 4096, DD, 0, 0, nullptr, mid, 0, bm1, nullptr, nullptr);
  // out = mid @ W2 + b2 + x2 fp32 [16384,1024]  (add == Cf, safe)
  gemm_bt<EPI_MLP2><<<dim3(DD / 128, MM / 128, 1), 256, 0, stream>>>(
      mid, w2t, MM, DD, 4096, 0, 0, out, nullptr, 0, bm2, x2, nullptr);
}

// Round 3
// 785.722 us; speedup vs baseline: 1.1358x; 1.1358x over previous
//
#include <hip/hip_runtime.h>
#include <hip/hip_bf16.h>
#include <stdint.h>

typedef __hip_bfloat16 bf16;
typedef __attribute__((ext_vector_type(4))) float f32x4;
typedef __attribute__((ext_vector_type(8))) short bf16x8;

// Problem constants
#define BB   8
#define TT   2048
#define DD   1024
#define MM   (BB * TT)   // 16384 rows

enum { EPI_Q = 0, EPI_K, EPI_V, EPI_ND, EPI_MLP1, EPI_MLP2 };

static __device__ __forceinline__ void async_ld16(const bf16* g, bf16* l) {
  __builtin_amdgcn_global_load_lds(
      (const __attribute__((address_space(1))) void*)g,
      (__attribute__((address_space(3))) void*)l, 16, 0, 0);
}

// ---------------------------------------------------------------------------
// Universal GEMM: C[M,N] = A[M,K] @ B[N,K]^T, A/B bf16 row-major (K inner).
// 128x128 tile, BK=64 (32 MFMA per barrier), 256 threads (4 waves, 2x2),
// each wave 64x64 via 4x4 grid of 16x16x32 MFMAs.
// LDS rows hold 8 16B-chunks; chunk c of row r stores global chunk c^(r&7)
// (XOR swizzle baked into the per-lane global_load_lds source address) so
// fragment ds_read_b128 is 2-way bank-aliased = conflict-free (m136).
// EPI_ND decodes batch from blockIdx.x (batch-fastest for ew/ekv L2 reuse).
// ---------------------------------------------------------------------------
template<int EPI>
__global__ __launch_bounds__(256, 2)
void gemm_bt(const bf16* __restrict__ A, const bf16* __restrict__ B,
             int M, int N, int K,
             long long strideAz, long long strideBz,
             float* __restrict__ Cf,
             bf16* __restrict__ Cb, long long strideCz,
             const float* __restrict__ bias,
             const float* __restrict__ add,
             bf16* __restrict__ ekv)
{
  (void)M;
  __shared__ __align__(16) bf16 As[128 * 64];
  __shared__ __align__(16) bf16 Bs[128 * 64];

  const int tid  = threadIdx.x;
  const int wave = tid >> 6;
  const int lane = tid & 63;
  int bn, bm, bz;
  if constexpr (EPI == EPI_ND) {  // batch-fastest
    bz = blockIdx.x; bn = blockIdx.y; bm = blockIdx.z;
  } else {
    bn = blockIdx.x; bm = blockIdx.y; bz = 0;
  }
  A += (size_t)bz * strideAz;
  B += (size_t)bz * strideBz;

  const int wm = (wave >> 1) * 64;   // wave's 64x64 sub-tile
  const int wn = (wave & 1) * 64;

  // staging: wave stages 32 rows of As and Bs; 8 rows per instr (128B rows),
  // lane l -> row l>>3, chunk l&7; source chunk = (l&7) ^ (sr&7)  (swizzle).
  const int sr = lane >> 3;                       // 0..7
  const int sc = (((lane & 7) ^ sr) & 7) * 8;     // swizzled source col (elts)
  const size_t a_row = (size_t)bm * 128 + wave * 32 + sr;
  const size_t b_row = (size_t)bn * 128 + wave * 32 + sr;
  const bf16* Ag = A + a_row * (size_t)K + sc;
  const bf16* Bg = B + b_row * (size_t)K + sc;
  bf16* Al = &As[(wave * 32) * 64];
  bf16* Bl = &Bs[(wave * 32) * 64];
  const size_t K8 = (size_t)8 * K;

  const int fm  = lane & 15;   // fragment row
  const int q4  = lane >> 4;   // fragment chunk quarter (0..3)
  const int fm7 = fm & 7;

  f32x4 acc[4][4];
#pragma unroll
  for (int i = 0; i < 4; ++i)
#pragma unroll
    for (int j = 0; j < 4; ++j) acc[i][j] = {0.f, 0.f, 0.f, 0.f};

  for (int k0 = 0; k0 < K; k0 += 64) {
#pragma unroll
    for (int o = 0; o < 4; ++o) {
      async_ld16(Ag + k0 + o * K8, Al + o * 8 * 64);
      async_ld16(Bg + k0 + o * K8, Bl + o * 8 * 64);
    }
    __builtin_amdgcn_s_waitcnt(0);
    __syncthreads();

#pragma unroll
    for (int h = 0; h < 2; ++h) {
      bf16x8 af[4], bfv[4];
#pragma unroll
      for (int i = 0; i < 4; ++i) {
        const int ca = ((h * 4 + q4) ^ fm7) * 8;
        af[i]  = *(const bf16x8*)&As[(wm + i * 16 + fm) * 64 + ca];
        bfv[i] = *(const bf16x8*)&Bs[(wn + i * 16 + fm) * 64 + ca];
      }
#pragma unroll
      for (int i = 0; i < 4; ++i)
#pragma unroll
        for (int j = 0; j < 4; ++j)
          acc[i][j] = __builtin_amdgcn_mfma_f32_16x16x32_bf16(
              af[i], bfv[j], acc[i][j], 0, 0, 0);
    }
    __syncthreads();
  }

  // epilogue: C/D layout col=lane&15, row=(lane>>4)*4+reg
  const int cr = (lane >> 4) * 4;
  const int cc = lane & 15;
#pragma unroll
  for (int i = 0; i < 4; ++i) {
#pragma unroll
    for (int j = 0; j < 4; ++j) {
#pragma unroll
      for (int r = 0; r < 4; ++r) {
        const int gm = bm * 128 + wm + i * 16 + cr + r;
        const int gn = bn * 128 + wn + j * 16 + cc;
        float v = acc[i][j][r];
        if constexpr (EPI == EPI_Q) {
          v += bias[gn];
          Cb[(size_t)gm * N + gn] = __float2bfloat16(v);
        } else if constexpr (EPI == EPI_K) {
          // gm = d, gn = global s. ekvT[b][1024+d][t] = exp(k)
          v = __expf(v + bias[gm]);
          const int b = gn >> 11, t = gn & (TT - 1);
          ekv[((size_t)b << 22) + (size_t)(1024 + gm) * TT + t] =
              __float2bfloat16(v);
        } else if constexpr (EPI == EPI_V) {
          // ekvT[b][d][t] = ek * v
          v += bias[gm];
          const int b = gn >> 11, t = gn & (TT - 1);
          const size_t base = ((size_t)b << 22);
          const float ek =
              __bfloat162float(ekv[base + (size_t)(1024 + gm) * TT + t]);
          ekv[base + (size_t)gm * TT + t] = __float2bfloat16(v * ek);
        } else if constexpr (EPI == EPI_ND) {
          Cb[(size_t)bz * strideCz + (size_t)gm * N + gn] =
              __float2bfloat16(v);
        } else if constexpr (EPI == EPI_MLP1) {
          v = fmaxf(v + bias[gn], 0.0f);
          Cb[(size_t)gm * N + gn] = __float2bfloat16(v);
        } else {  // EPI_MLP2: add == Cf aliasing is safe (read-then-write
          // of the same element within the same thread)
          v += bias[gn] + add[(size_t)gm * N + gn];
          Cf[(size_t)gm * N + gn] = v;
        }
      }
    }
  }
}

// ---------------------------------------------------------------------------
// Transpose + cast fp32 [K,N] -> bf16 [N,K] (LDS tiled)
// ---------------------------------------------------------------------------
__global__ __launch_bounds__(256)
void transpose_cast(const float* __restrict__ W, bf16* __restrict__ Wt,
                    int K, int N)
{
  __shared__ float tile[32][33];
  const int n0 = blockIdx.x * 32, k0 = blockIdx.y * 32;
  const int tx = threadIdx.x, ty = threadIdx.y;  // 32 x 8
#pragma unroll
  for (int i = 0; i < 32; i += 8)
    tile[ty + i][tx] = W[(size_t)(k0 + ty + i) * N + n0 + tx];
  __syncthreads();
#pragma unroll
  for (int i = 0; i < 32; i += 8)
    Wt[(size_t)(n0 + ty + i) * K + k0 + tx] =
        __float2bfloat16(tile[tx][ty + i]);
}

// ---------------------------------------------------------------------------
// ew = exp(pos_bias) as bf16 (global max cancels in num/den ratio)
// ---------------------------------------------------------------------------
__global__ __launch_bounds__(256)
void ew_kernel(const float* __restrict__ pb, bf16* __restrict__ ew)
{
  const size_t gid = (size_t)blockIdx.x * 256 + threadIdx.x;
  const float4 v = *(const float4*)(pb + gid * 4);
  union { bf16 h[4]; unsigned long long u; } pk;
  pk.h[0] = __float2bfloat16(__expf(v.x));
  pk.h[1] = __float2bfloat16(__expf(v.y));
  pk.h[2] = __float2bfloat16(__expf(v.z));
  pk.h[3] = __float2bfloat16(__expf(v.w));
  *(unsigned long long*)(ew + gid * 4) = pk.u;
}

// ---------------------------------------------------------------------------
// LayerNorm over D=1024, one block per row, output bf16
// ---------------------------------------------------------------------------
__global__ __launch_bounds__(256)
void ln_kernel(const float* __restrict__ x, const float* __restrict__ g,
               const float* __restrict__ b, bf16* __restrict__ out)
{
  const int row = blockIdx.x;
  const int tid = threadIdx.x;
  const float4 v = ((const float4*)(x + (size_t)row * DD))[tid];
  float s  = v.x + v.y + v.z + v.w;
  float s2 = v.x * v.x + v.y * v.y + v.z * v.z + v.w * v.w;
#pragma unroll
  for (int o = 32; o; o >>= 1) {
    s  += __shfl_down(s, o);
    s2 += __shfl_down(s2, o);
  }
  __shared__ float red[8];
  if ((tid & 63) == 0) { red[tid >> 6] = s; red[4 + (tid >> 6)] = s2; }
  __syncthreads();
  const float ts  = red[0] + red[1] + red[2] + red[3];
  const float ts2 = red[4] + red[5] + red[6] + red[7];
  const float mu = ts * (1.0f / DD);
  const float rs = rsqrtf(ts2 * (1.0f / DD) - mu * mu + 1e-5f);
  const float4 gv = ((const float4*)g)[tid];
  const float4 bv = ((const float4*)b)[tid];
  union { bf16 h[4]; unsigned long long u; } pk;
  pk.h[0] = __float2bfloat16((v.x - mu) * rs * gv.x + bv.x);
  pk.h[1] = __float2bfloat16((v.y - mu) * rs * gv.y + bv.y);
  pk.h[2] = __float2bfloat16((v.z - mu) * rs * gv.z + bv.z);
  pk.h[3] = __float2bfloat16((v.w - mu) * rs * gv.w + bv.w);
  ((unsigned long long*)(out + (size_t)row * DD))[tid] = pk.u;
}

// ---------------------------------------------------------------------------
// Fused: x2 = sigmoid(q) * num/den + x  (x2 aliases d_out), then
// h2 = LN(x2, g2, b2) -> hout bf16.  One block per row.
// ---------------------------------------------------------------------------
__global__ __launch_bounds__(256)
void combine_ln_kernel(const bf16* __restrict__ q, const bf16* __restrict__ nd,
                       const float* __restrict__ x,
                       const float* __restrict__ g, const float* __restrict__ b,
                       float* __restrict__ x2, bf16* __restrict__ hout)
{
  const int row = blockIdx.x;
  const int tid = threadIdx.x;
  const int c = tid * 4;
  const bf16* ndr = nd + (size_t)row * 2048;
  union { unsigned long long u; bf16 h[4]; } un, ud, uq;
  un.u = *(const unsigned long long*)(ndr + c);
  ud.u = *(const unsigned long long*)(ndr + 1024 + c);
  uq.u = *(const unsigned long long*)(q + (size_t)row * DD + c);
  const float4 xv = *(const float4*)(x + (size_t)row * DD + c);
  float4 o;
  o.x = xv.x + (__bfloat162float(un.h[0]) / __bfloat162float(ud.h[0])) /
                   (1.0f + __expf(-__bfloat162float(uq.h[0])));
  o.y = xv.y + (__bfloat162float(un.h[1]) / __bfloat162float(ud.h[1])) /
                   (1.0f + __expf(-__bfloat162float(uq.h[1])));
  o.z = xv.z + (__bfloat162float(un.h[2]) / __bfloat162float(ud.h[2])) /
                   (1.0f + __expf(-__bfloat162float(uq.h[2])));
  o.w = xv.w + (__bfloat162float(un.h[3]) / __bfloat162float(ud.h[3])) /
                   (1.0f + __expf(-__bfloat162float(uq.h[3])));
  *(float4*)(x2 + (size_t)row * DD + c) = o;

  // ---- LayerNorm of o across the row ----
  float s  = o.x + o.y + o.z + o.w;
  float s2 = o.x * o.x + o.y * o.y + o.z * o.z + o.w * o.w;
#pragma unroll
  for (int off = 32; off; off >>= 1) {
    s  += __shfl_down(s, off);
    s2 += __shfl_down(s2, off);
  }
  __shared__ float red[8];
  if ((tid & 63) == 0) { red[tid >> 6] = s; red[4 + (tid >> 6)] = s2; }
  __syncthreads();
  const float ts  = red[0] + red[1] + red[2] + red[3];
  const float ts2 = red[4] + red[5] + red[6] + red[7];
  const float mu = ts * (1.0f / DD);
  const float rs = rsqrtf(ts2 * (1.0f / DD) - mu * mu + 1e-5f);
  const float4 gv = ((const float4*)g)[tid];
  const float4 bv = ((const float4*)b)[tid];
  union { bf16 h[4]; unsigned long long u; } pk;
  pk.h[0] = __float2bfloat16((o.x - mu) * rs * gv.x + bv.x);
  pk.h[1] = __float2bfloat16((o.y - mu) * rs * gv.y + bv.y);
  pk.h[2] = __float2bfloat16((o.z - mu) * rs * gv.z + bv.z);
  pk.h[3] = __float2bfloat16((o.w - mu) * rs * gv.w + bv.w);
  ((unsigned long long*)(hout + (size_t)row * DD))[tid] = pk.u;
}

// ---------------------------------------------------------------------------
extern "C" void kernel_launch(void* const* d_in, const int* in_sizes, int n_in,
                              void* d_out, int out_size, void* d_ws,
                              size_t ws_size, hipStream_t stream)
{
  (void)in_sizes; (void)n_in; (void)out_size; (void)ws_size;
  const float* x   = (const float*)d_in[0];
  const float* Wq  = (const float*)d_in[1];
  const float* bq  = (const float*)d_in[2];
  const float* Wk  = (const float*)d_in[3];
  const float* bk  = (const float*)d_in[4];
  const float* Wv  = (const float*)d_in[5];
  const float* bv  = (const float*)d_in[6];
  const float* pb  = (const float*)d_in[7];
  const float* g1  = (const float*)d_in[8];
  const float* be1 = (const float*)d_in[9];
  const float* W1  = (const float*)d_in[10];
  const float* bm1 = (const float*)d_in[11];
  const float* W2  = (const float*)d_in[12];
  const float* bm2 = (const float*)d_in[13];
  const float* g2  = (const float*)d_in[14];
  const float* be2 = (const float*)d_in[15];
  float* out = (float*)d_out;

  // ---- workspace layout: 222 MiB total ----
  const size_t MiB = 1024 * 1024;
  char* w = (char*)d_ws;
  bf16* hbf = (bf16*)w;  w += (size_t)MM * DD * 2;        // 32 MiB (h, then h2)
  bf16* wqt = (bf16*)w;  w += (size_t)DD * DD * 2;        // 2 MiB
  bf16* wkt = (bf16*)w;  w += (size_t)DD * DD * 2;
  bf16* wvt = (bf16*)w;  w += (size_t)DD * DD * 2;
  bf16* w1t = (bf16*)w;  w += (size_t)4096 * DD * 2;      // 8 MiB
  bf16* w2t = (bf16*)w;  w += (size_t)DD * 4096 * 2;      // 8 MiB
  // scratch region (168 MiB), fully dead after combine_ln_kernel:
  char* scr = w;
  bf16* qbf = (bf16*)scr;                                  // 32 MiB
  bf16* ewb = (bf16*)(scr + 32 * MiB);                     // 8 MiB
  bf16* ekv = (bf16*)(scr + 40 * MiB);   // 64 MiB [b][2048: 0..1023=ek*v, 1024..2047=ek][t]
  bf16* nd  = (bf16*)(scr + 104 * MiB);  // 64 MiB [b][t][2048: num|den]
  bf16* mid = (bf16*)scr;                // 128 MiB, overlays scratch after combine
  float* x2 = out;                       // alias: residual lives in d_out

  const dim3 tb(32, 8);
  transpose_cast<<<dim3(DD / 32, DD / 32), tb, 0, stream>>>(Wq, wqt, DD, DD);
  transpose_cast<<<dim3(DD / 32, DD / 32), tb, 0, stream>>>(Wk, wkt, DD, DD);
  transpose_cast<<<dim3(DD / 32, DD / 32), tb, 0, stream>>>(Wv, wvt, DD, DD);
  transpose_cast<<<dim3(4096 / 32, DD / 32), tb, 0, stream>>>(W1, w1t, DD, 4096);
  transpose_cast<<<dim3(DD / 32, 4096 / 32), tb, 0, stream>>>(W2, w2t, 4096, DD);

  ew_kernel<<<(TT * TT / 4) / 256, 256, 0, stream>>>(pb, ewb);
  ln_kernel<<<MM, 256, 0, stream>>>(x, g1, be1, hbf);

  // q = h @ Wq + bq  -> qbf [16384,1024] bf16
  gemm_bt<EPI_Q><<<dim3(DD / 128, MM / 128, 1), 256, 0, stream>>>(
      hbf, wqt, MM, DD, DD, 0, 0, nullptr, qbf, 0, bq, nullptr, nullptr);
  // ek^T: C[d, s] = Wkt @ h^T, epilogue exp -> ekv rows 1024..2047
  gemm_bt<EPI_K><<<dim3(MM / 128, DD / 128, 1), 256, 0, stream>>>(
      wkt, hbf, DD, MM, DD, 0, 0, nullptr, nullptr, 0, bk, nullptr, ekv);
  // v^T: epilogue *ek -> ekv rows 0..1023
  gemm_bt<EPI_V><<<dim3(MM / 128, DD / 128, 1), 256, 0, stream>>>(
      wvt, hbf, DD, MM, DD, 0, 0, nullptr, nullptr, 0, bv, nullptr, ekv);
  // nd[b] = ew @ ekv[b]^T : [2048,2048] bf16 per batch (batch-fastest grid)
  gemm_bt<EPI_ND><<<dim3(BB, TT / 128, TT / 128), 256, 0, stream>>>(
      ewb, ekv, TT, TT, TT, 0, (long long)TT * TT, nullptr, nd,
      (long long)TT * TT, nullptr, nullptr, nullptr);

  // fused: x2 = sigmoid(q)*num/den + x ; hbf = LN(x2)
  combine_ln_kernel<<<MM, 256, 0, stream>>>(qbf, nd, x, g2, be2, x2, hbf);

  // mid = relu(h2 @ W1 + b1) bf16 [16384,4096]
  gemm_bt<EPI_MLP1><<<dim3(4096 / 128, MM / 128, 1), 256, 0, stream>>>(
      hbf, w1t, MM, 4096, DD, 0, 0, nullptr, mid, 0, bm1, nullptr, nullptr);
  // out = mid @ W2 + b2 + x2 fp32 [16384,1024]  (add == Cf, safe)
  gemm_bt<EPI_MLP2><<<dim3(DD / 128, MM / 128, 1), 256, 0, stream>>>(
      mid, w2t, MM, DD, 4096, 0, 0, out, nullptr, 0, bm2, x2, nullptr);
}